// Round 1
// baseline (560.532 us; speedup 1.0000x reference)
//
#include <hip/hip_runtime.h>

#define N_NODES 50000
#define N_EDGES 800000
#define N_GRAPHS 128
#define D 128
#define NCHUNK 196           // ceil(50000/256)

// ---------------------------------------------------------------- CSR build
__global__ __launch_bounds__(256) void k_count(const int* __restrict__ col,
                                               int* __restrict__ counts) {
    int e = blockIdx.x * 256 + threadIdx.x;
    if (e < N_EDGES) atomicAdd(&counts[col[e]], 1);
}

__global__ __launch_bounds__(256) void k_dinv(const int* __restrict__ counts,
                                              float* __restrict__ dinv) {
    int i = blockIdx.x * 256 + threadIdx.x;
    if (i < N_NODES) dinv[i] = rsqrtf((float)(counts[i] + 1)); // +1 self loop
}

__global__ __launch_bounds__(256) void k_chunksum(const int* __restrict__ counts,
                                                  int* __restrict__ partials) {
    __shared__ int s[256];
    int i = blockIdx.x * 256 + threadIdx.x;
    s[threadIdx.x] = (i < N_NODES) ? counts[i] : 0;
    __syncthreads();
    for (int off = 128; off > 0; off >>= 1) {
        if (threadIdx.x < off) s[threadIdx.x] += s[threadIdx.x + off];
        __syncthreads();
    }
    if (threadIdx.x == 0) partials[blockIdx.x] = s[0];
}

__global__ __launch_bounds__(256) void k_scanpart(int* __restrict__ partials, int m) {
    __shared__ int s[256];
    int t = threadIdx.x;
    int orig = (t < m) ? partials[t] : 0;
    s[t] = orig;
    __syncthreads();
    for (int off = 1; off < 256; off <<= 1) {
        int v = (t >= off) ? s[t - off] : 0;
        __syncthreads();
        s[t] += v;
        __syncthreads();
    }
    if (t < m) partials[t] = s[t] - orig;   // exclusive
}

__global__ __launch_bounds__(256) void k_scanchunk(const int* __restrict__ counts,
                                                   const int* __restrict__ partials,
                                                   int* __restrict__ row_ptr,
                                                   int* __restrict__ offs) {
    __shared__ int s[256];
    int i = blockIdx.x * 256 + threadIdx.x;
    int t = threadIdx.x;
    int orig = (i < N_NODES) ? counts[i] : 0;
    s[t] = orig;
    __syncthreads();
    for (int off = 1; off < 256; off <<= 1) {
        int v = (t >= off) ? s[t - off] : 0;
        __syncthreads();
        s[t] += v;
        __syncthreads();
    }
    int ex = s[t] - orig + partials[blockIdx.x];
    if (i < N_NODES) { row_ptr[i] = ex; offs[i] = ex; }
    if (i == N_NODES - 1) row_ptr[N_NODES] = ex + orig;
}

__global__ __launch_bounds__(256) void k_fill(const int* __restrict__ row,
                                              const int* __restrict__ col,
                                              const float* __restrict__ dinv,
                                              int* __restrict__ offs,
                                              int* __restrict__ esrc,
                                              float* __restrict__ ew) {
    int e = blockIdx.x * 256 + threadIdx.x;
    if (e < N_EDGES) {
        int c = col[e], r = row[e];
        int pos = atomicAdd(&offs[c], 1);
        esrc[pos] = r;
        ew[pos] = dinv[r];                  // dinv[dst] applied at node level
    }
}

// ---------------------------------------------------------------- GEMM  (N x 128) @ (128 x 128)
__global__ __launch_bounds__(256) void k_gemm(const float* __restrict__ H,
                                              const float* __restrict__ W,
                                              float* __restrict__ out, int n) {
    __shared__ float Ws[128 * 128];   // 64 KB
    __shared__ float Hs[32 * 128];    // 16 KB
    const int tid = threadIdx.x;
    const int row0 = blockIdx.x * 32;
    {
        const float4* W4 = (const float4*)W;
        float4* Ws4 = (float4*)Ws;
#pragma unroll
        for (int i = 0; i < 16; ++i) Ws4[tid + i * 256] = W4[tid + i * 256];
        const int rows = min(32, n - row0);
        const float4* H4 = (const float4*)(H + (size_t)row0 * D);
        float4* Hs4 = (float4*)Hs;
        for (int i = tid; i < rows * 32; i += 256) Hs4[i] = H4[i];
    }
    __syncthreads();
    const int tx = tid & 31, ty = tid >> 5;   // ty 0..7 -> 4 rows each
    float acc[4][4] = {};
#pragma unroll 4
    for (int k = 0; k < 128; ++k) {
        float b0 = Ws[k * 128 + tx];
        float b1 = Ws[k * 128 + tx + 32];
        float b2 = Ws[k * 128 + tx + 64];
        float b3 = Ws[k * 128 + tx + 96];
#pragma unroll
        for (int r = 0; r < 4; ++r) {
            float a = Hs[(ty * 4 + r) * 128 + k];
            acc[r][0] += a * b0;
            acc[r][1] += a * b1;
            acc[r][2] += a * b2;
            acc[r][3] += a * b3;
        }
    }
    const int rows = n - row0;
#pragma unroll
    for (int r = 0; r < 4; ++r) {
        int rr = ty * 4 + r;
        if (rr < rows) {
            float* o = out + (size_t)(row0 + rr) * D;
            o[tx]      = acc[r][0];
            o[tx + 32] = acc[r][1];
            o[tx + 64] = acc[r][2];
            o[tx + 96] = acc[r][3];
        }
    }
}

// ---------------------------------------------------------------- aggregation (gather, no atomics)
template <int RELU>
__global__ __launch_bounds__(256) void k_agg(const float* __restrict__ HW,
                                             const int* __restrict__ rp,
                                             const int* __restrict__ esrc,
                                             const float* __restrict__ ew,
                                             const float* __restrict__ dinv,
                                             const float* __restrict__ bias,
                                             float* __restrict__ out) {
    int c = (blockIdx.x * blockDim.x + threadIdx.x) >> 6;   // one wave per node
    int lane = threadIdx.x & 63;
    if (c >= N_NODES) return;
    int beg = rp[c], end = rp[c + 1];
    float acc0 = 0.f, acc1 = 0.f;
    int j = beg;
    for (; j + 1 < end; j += 2) {
        int s0 = esrc[j], s1 = esrc[j + 1];
        float w0 = ew[j], w1 = ew[j + 1];
        const float* h0 = HW + (size_t)s0 * D;
        const float* h1 = HW + (size_t)s1 * D;
        acc0 += w0 * h0[lane];
        acc1 += w0 * h0[lane + 64];
        acc0 += w1 * h1[lane];
        acc1 += w1 * h1[lane + 64];
    }
    if (j < end) {
        int s0 = esrc[j];
        float w0 = ew[j];
        const float* h0 = HW + (size_t)s0 * D;
        acc0 += w0 * h0[lane];
        acc1 += w0 * h0[lane + 64];
    }
    float dv = dinv[c];
    const float* hc = HW + (size_t)c * D;
    acc0 += dv * hc[lane];                    // self loop
    acc1 += dv * hc[lane + 64];
    acc0 = dv * acc0 + bias[lane];
    acc1 = dv * acc1 + bias[lane + 64];
    if (RELU) { acc0 = fmaxf(acc0, 0.f); acc1 = fmaxf(acc1, 0.f); }
    out[(size_t)c * D + lane]      = acc0;
    out[(size_t)c * D + lane + 64] = acc1;
}

// ---------------------------------------------------------------- mean pool (sorted batch, few atomics)
__global__ __launch_bounds__(128) void k_pool(const float* __restrict__ h,
                                              const int* __restrict__ batch,
                                              float* __restrict__ psum,
                                              float* __restrict__ pcnt) {
    int d = threadIdx.x;                       // 128 threads = feature dims
    int start = blockIdx.x * 256;
    int end = min(start + 256, N_NODES);
    if (start >= N_NODES) return;
    float acc = 0.f, cnt = 0.f;
    int g = batch[start];
    for (int i = start; i < end; ++i) {
        int gi = batch[i];
        if (gi != g) {
            atomicAdd(&psum[g * D + d], acc);
            if (d == 0) atomicAdd(&pcnt[g], cnt);
            acc = 0.f; cnt = 0.f; g = gi;
        }
        acc += h[(size_t)i * D + d];
        cnt += 1.f;
    }
    atomicAdd(&psum[g * D + d], acc);
    if (d == 0) atomicAdd(&pcnt[g], cnt);
}

__global__ __launch_bounds__(384) void k_final(const float* __restrict__ psum,
                                               const float* __restrict__ pcnt,
                                               const float* __restrict__ Wlin,
                                               const float* __restrict__ blin,
                                               float* __restrict__ out) {
    int t = threadIdx.x;
    if (t >= N_GRAPHS * 3) return;
    int g = t / 3, o = t % 3;
    float c = fmaxf(pcnt[g], 1.f);
    float acc = 0.f;
#pragma unroll 8
    for (int d = 0; d < D; ++d) acc += psum[g * D + d] * Wlin[d * 3 + o];
    out[t] = acc / c + blin[o];
}

// ---------------------------------------------------------------- launch
extern "C" void kernel_launch(void* const* d_in, const int* in_sizes, int n_in,
                              void* d_out, int out_size, void* d_ws, size_t ws_size,
                              hipStream_t stream) {
    const float* x    = (const float*)d_in[0];
    const int*   row  = (const int*)d_in[1];            // edge_index[0]
    const int*   col  = ((const int*)d_in[1]) + N_EDGES; // edge_index[1]
    const int*   batch = (const int*)d_in[2];
    const float* W1 = (const float*)d_in[3];  const float* b1 = (const float*)d_in[4];
    const float* W2 = (const float*)d_in[5];  const float* b2 = (const float*)d_in[6];
    const float* W3 = (const float*)d_in[7];  const float* b3 = (const float*)d_in[8];
    const float* Wlin = (const float*)d_in[9]; const float* blin = (const float*)d_in[10];
    float* out = (float*)d_out;

    char* w = (char*)d_ws;
    size_t off = 0;
    auto alloc = [&](size_t bytes) { void* p = w + off; off += (bytes + 255) & ~(size_t)255; return p; };
    float* dinv    = (float*)alloc(N_NODES * 4);
    int*   counts  = (int*)alloc(N_NODES * 4);
    int*   row_ptr = (int*)alloc((N_NODES + 1) * 4);
    int*   offs    = (int*)alloc(N_NODES * 4);
    int*   partials= (int*)alloc(256 * 4);
    int*   esrc    = (int*)alloc((size_t)N_EDGES * 4);
    float* ew      = (float*)alloc((size_t)N_EDGES * 4);
    float* bufA    = (float*)alloc((size_t)N_NODES * D * 4);
    float* bufB    = (float*)alloc((size_t)N_NODES * D * 4);
    float* psum    = (float*)alloc(N_GRAPHS * D * 4);
    float* pcnt    = (float*)alloc(N_GRAPHS * 4);

    hipMemsetAsync(counts, 0, N_NODES * 4, stream);
    hipMemsetAsync(psum, 0, N_GRAPHS * D * 4, stream);
    hipMemsetAsync(pcnt, 0, N_GRAPHS * 4, stream);

    const int EB = (N_EDGES + 255) / 256;   // 3125
    k_count<<<EB, 256, 0, stream>>>(col, counts);
    k_dinv<<<NCHUNK, 256, 0, stream>>>(counts, dinv);
    k_chunksum<<<NCHUNK, 256, 0, stream>>>(counts, partials);
    k_scanpart<<<1, 256, 0, stream>>>(partials, NCHUNK);
    k_scanchunk<<<NCHUNK, 256, 0, stream>>>(counts, partials, row_ptr, offs);
    k_fill<<<EB, 256, 0, stream>>>(row, col, dinv, offs, esrc, ew);

    const int GB = (N_NODES + 31) / 32;     // 1563 gemm blocks
    const int AB = (N_NODES * 64 + 255) / 256; // 12500 agg blocks (1 wave/node)

    k_gemm<<<GB, 256, 0, stream>>>(x, W1, bufA, N_NODES);
    k_agg<1><<<AB, 256, 0, stream>>>(bufA, row_ptr, esrc, ew, dinv, b1, bufB);
    k_gemm<<<GB, 256, 0, stream>>>(bufB, W2, bufA, N_NODES);
    k_agg<1><<<AB, 256, 0, stream>>>(bufA, row_ptr, esrc, ew, dinv, b2, bufB);
    k_gemm<<<GB, 256, 0, stream>>>(bufB, W3, bufA, N_NODES);
    k_agg<0><<<AB, 256, 0, stream>>>(bufA, row_ptr, esrc, ew, dinv, b3, bufB);

    k_pool<<<NCHUNK, 128, 0, stream>>>(bufB, batch, psum, pcnt);
    k_final<<<1, 384, 0, stream>>>(psum, pcnt, Wlin, blin, out);
}

// Round 3
// 524.325 us; speedup vs baseline: 1.0691x; 1.0691x over previous
//
#include <hip/hip_runtime.h>

#define N_NODES 50000
#define N_EDGES 800000
#define N_GRAPHS 128
#define D 128
#define NCHUNK 196           // ceil(50000/256)

__device__ __forceinline__ void fma4(float4& a, float w, const float4& h) {
    a.x += w * h.x; a.y += w * h.y; a.z += w * h.z; a.w += w * h.w;
}

// ---------------------------------------------------------------- CSR build
__global__ __launch_bounds__(256) void k_count(const int* __restrict__ col,
                                               int* __restrict__ counts) {
    int e = blockIdx.x * 256 + threadIdx.x;
    if (e < N_EDGES) atomicAdd(&counts[col[e]], 1);
}

__global__ __launch_bounds__(256) void k_dinv(const int* __restrict__ counts,
                                              float* __restrict__ dinv) {
    int i = blockIdx.x * 256 + threadIdx.x;
    if (i < N_NODES) dinv[i] = rsqrtf((float)(counts[i] + 1)); // +1 self loop
}

__global__ __launch_bounds__(256) void k_chunksum(const int* __restrict__ counts,
                                                  int* __restrict__ partials) {
    __shared__ int s[256];
    int i = blockIdx.x * 256 + threadIdx.x;
    s[threadIdx.x] = (i < N_NODES) ? counts[i] : 0;
    __syncthreads();
    for (int off = 128; off > 0; off >>= 1) {
        if (threadIdx.x < off) s[threadIdx.x] += s[threadIdx.x + off];
        __syncthreads();
    }
    if (threadIdx.x == 0) partials[blockIdx.x] = s[0];
}

__global__ __launch_bounds__(256) void k_scanpart(int* __restrict__ partials, int m) {
    __shared__ int s[256];
    int t = threadIdx.x;
    int orig = (t < m) ? partials[t] : 0;
    s[t] = orig;
    __syncthreads();
    for (int off = 1; off < 256; off <<= 1) {
        int v = (t >= off) ? s[t - off] : 0;
        __syncthreads();
        s[t] += v;
        __syncthreads();
    }
    if (t < m) partials[t] = s[t] - orig;   // exclusive
}

__global__ __launch_bounds__(256) void k_scanchunk(const int* __restrict__ counts,
                                                   const int* __restrict__ partials,
                                                   int* __restrict__ row_ptr,
                                                   int* __restrict__ offs) {
    __shared__ int s[256];
    int i = blockIdx.x * 256 + threadIdx.x;
    int t = threadIdx.x;
    int orig = (i < N_NODES) ? counts[i] : 0;
    s[t] = orig;
    __syncthreads();
    for (int off = 1; off < 256; off <<= 1) {
        int v = (t >= off) ? s[t - off] : 0;
        __syncthreads();
        s[t] += v;
        __syncthreads();
    }
    int ex = s[t] - orig + partials[blockIdx.x];
    if (i < N_NODES) { row_ptr[i] = ex; offs[i] = ex; }
    if (i == N_NODES - 1) row_ptr[N_NODES] = ex + orig;
}

__global__ __launch_bounds__(256) void k_fill(const int* __restrict__ row,
                                              const int* __restrict__ col,
                                              const float* __restrict__ dinv,
                                              int* __restrict__ offs,
                                              int2* __restrict__ e2) {
    int e = blockIdx.x * 256 + threadIdx.x;
    if (e < N_EDGES) {
        int c = col[e], r = row[e];
        int pos = atomicAdd(&offs[c], 1);
        e2[pos] = make_int2(r, __float_as_int(dinv[r])); // (src, dinv[src])
    }
}

// ---------------------------------------------------------------- GEMM  (N x 128) @ (128 x 128)
// thread (tx,ty): cols [4tx..4tx+3], rows [4ty..4ty+3]; k unrolled by 4, all-b128 LDS reads
__global__ __launch_bounds__(256) void k_gemm(const float* __restrict__ H,
                                              const float* __restrict__ W,
                                              float* __restrict__ out, int n) {
    __shared__ float Ws[128 * 128];   // 64 KB
    __shared__ float Hs[32 * 128];    // 16 KB
    const int tid = threadIdx.x;
    const int row0 = blockIdx.x * 32;
    {
        const float4* W4 = (const float4*)W;
        float4* Ws4 = (float4*)Ws;
#pragma unroll
        for (int i = 0; i < 16; ++i) Ws4[tid + i * 256] = W4[tid + i * 256];
        const int rows = min(32, n - row0);
        const float4* H4 = (const float4*)(H + (size_t)row0 * D);
        float4* Hs4 = (float4*)Hs;
        for (int i = tid; i < rows * 32; i += 256) Hs4[i] = H4[i];
    }
    __syncthreads();
    const int tx = tid & 31, ty = tid >> 5;
    const float4* HsR = (const float4*)Hs;
    const float4* WsR = (const float4*)Ws;
    float4 acc0 = {0,0,0,0}, acc1 = {0,0,0,0}, acc2 = {0,0,0,0}, acc3 = {0,0,0,0};
#pragma unroll 8
    for (int k4 = 0; k4 < 32; ++k4) {
        float4 a0 = HsR[(ty * 4 + 0) * 32 + k4];
        float4 a1 = HsR[(ty * 4 + 1) * 32 + k4];
        float4 a2 = HsR[(ty * 4 + 2) * 32 + k4];
        float4 a3 = HsR[(ty * 4 + 3) * 32 + k4];
        float4 b0 = WsR[(k4 * 4 + 0) * 32 + tx];
        float4 b1 = WsR[(k4 * 4 + 1) * 32 + tx];
        float4 b2 = WsR[(k4 * 4 + 2) * 32 + tx];
        float4 b3 = WsR[(k4 * 4 + 3) * 32 + tx];
        fma4(acc0, a0.x, b0); fma4(acc0, a0.y, b1); fma4(acc0, a0.z, b2); fma4(acc0, a0.w, b3);
        fma4(acc1, a1.x, b0); fma4(acc1, a1.y, b1); fma4(acc1, a1.z, b2); fma4(acc1, a1.w, b3);
        fma4(acc2, a2.x, b0); fma4(acc2, a2.y, b1); fma4(acc2, a2.z, b2); fma4(acc2, a2.w, b3);
        fma4(acc3, a3.x, b0); fma4(acc3, a3.y, b1); fma4(acc3, a3.z, b2); fma4(acc3, a3.w, b3);
    }
    const int rows = n - row0;
    float4* o = (float4*)(out + (size_t)row0 * D);
    if (ty * 4 + 0 < rows) o[(ty * 4 + 0) * 32 + tx] = acc0;
    if (ty * 4 + 1 < rows) o[(ty * 4 + 1) * 32 + tx] = acc1;
    if (ty * 4 + 2 < rows) o[(ty * 4 + 2) * 32 + tx] = acc2;
    if (ty * 4 + 3 < rows) o[(ty * 4 + 3) * 32 + tx] = acc3;
}

// ---------------------------------------------------------------- aggregation
// one wave per node; half-wave (32 lanes) per edge-row, float4 per lane (512 B row)
template <int RELU>
__global__ __launch_bounds__(256) void k_agg(const float* __restrict__ HW,
                                             const int* __restrict__ rp,
                                             const int2* __restrict__ e2,
                                             const float* __restrict__ dinv,
                                             const float* __restrict__ bias,
                                             float* __restrict__ out) {
    int wid = (blockIdx.x * 256 + threadIdx.x) >> 6;
    int c = __builtin_amdgcn_readfirstlane(wid);
    if (c >= N_NODES) return;
    const int lane = threadIdx.x & 63;
    const int half = lane >> 5;
    const int l = lane & 31;
    const float4* __restrict__ HW4 = (const float4*)HW;
    const int beg = rp[c], end = rp[c + 1];
    float4 acc0 = {0,0,0,0}, acc1 = {0,0,0,0};
    int j = beg;
    for (; j + 3 < end; j += 4) {
        int2 eA = e2[j + half];
        int2 eB = e2[j + 2 + half];
        float4 hA = HW4[(size_t)eA.x * 32 + l];
        float4 hB = HW4[(size_t)eB.x * 32 + l];
        fma4(acc0, __int_as_float(eA.y), hA);
        fma4(acc1, __int_as_float(eB.y), hB);
    }
    if (j + 1 < end) {
        int2 eA = e2[j + half];
        float4 hA = HW4[(size_t)eA.x * 32 + l];
        fma4(acc0, __int_as_float(eA.y), hA);
        j += 2;
    }
    const float dv = dinv[c];
    if (half == 0) {
        if (j < end) {                       // odd tail edge
            int2 eA = e2[j];
            fma4(acc0, __int_as_float(eA.y), HW4[(size_t)eA.x * 32 + l]);
        }
        fma4(acc0, dv, HW4[(size_t)c * 32 + l]);   // self loop
    }
    acc0.x += acc1.x; acc0.y += acc1.y; acc0.z += acc1.z; acc0.w += acc1.w;
    acc0.x += __shfl_xor(acc0.x, 32);
    acc0.y += __shfl_xor(acc0.y, 32);
    acc0.z += __shfl_xor(acc0.z, 32);
    acc0.w += __shfl_xor(acc0.w, 32);
    if (half == 0) {
        float4 bb = ((const float4*)bias)[l];
        float4 r;
        r.x = dv * acc0.x + bb.x;
        r.y = dv * acc0.y + bb.y;
        r.z = dv * acc0.z + bb.z;
        r.w = dv * acc0.w + bb.w;
        if (RELU) {
            r.x = fmaxf(r.x, 0.f); r.y = fmaxf(r.y, 0.f);
            r.z = fmaxf(r.z, 0.f); r.w = fmaxf(r.w, 0.f);
        }
        ((float4*)out)[(size_t)c * 32 + l] = r;
    }
}

// ---------------------------------------------------------------- mean pool (sorted batch)
__global__ __launch_bounds__(64) void k_pool(const float* __restrict__ h,
                                             const int* __restrict__ batch,
                                             float* __restrict__ psum,
                                             float* __restrict__ pcnt) {
    const int l = threadIdx.x;                 // 64 lanes, float2 each = 128 dims
    const int start = blockIdx.x * 32;
    if (start >= N_NODES) return;
    const int end = min(start + 32, N_NODES);
    const float2* __restrict__ h2 = (const float2*)h;
    float2 acc = {0.f, 0.f};
    float cnt = 0.f;
    int g = batch[start];
    for (int i = start; i < end; ++i) {
        int gi = batch[i];
        if (gi != g) {
            atomicAdd(&psum[g * D + 2 * l], acc.x);
            atomicAdd(&psum[g * D + 2 * l + 1], acc.y);
            if (l == 0) atomicAdd(&pcnt[g], cnt);
            acc.x = 0.f; acc.y = 0.f; cnt = 0.f; g = gi;
        }
        float2 v = h2[(size_t)i * 64 + l];
        acc.x += v.x; acc.y += v.y; cnt += 1.f;
    }
    atomicAdd(&psum[g * D + 2 * l], acc.x);
    atomicAdd(&psum[g * D + 2 * l + 1], acc.y);
    if (l == 0) atomicAdd(&pcnt[g], cnt);
}

__global__ __launch_bounds__(384) void k_final(const float* __restrict__ psum,
                                               const float* __restrict__ pcnt,
                                               const float* __restrict__ Wlin,
                                               const float* __restrict__ blin,
                                               float* __restrict__ out) {
    int t = threadIdx.x;
    if (t >= N_GRAPHS * 3) return;
    int g = t / 3, o = t % 3;
    float c = fmaxf(pcnt[g], 1.f);
    float acc = 0.f;
#pragma unroll 8
    for (int d = 0; d < D; ++d) acc += psum[g * D + d] * Wlin[d * 3 + o];
    out[t] = acc / c + blin[o];
}

// ---------------------------------------------------------------- launch
extern "C" void kernel_launch(void* const* d_in, const int* in_sizes, int n_in,
                              void* d_out, int out_size, void* d_ws, size_t ws_size,
                              hipStream_t stream) {
    const float* x    = (const float*)d_in[0];
    const int*   row  = (const int*)d_in[1];             // edge_index[0]
    const int*   col  = ((const int*)d_in[1]) + N_EDGES; // edge_index[1]
    const int*   batch = (const int*)d_in[2];
    const float* W1 = (const float*)d_in[3];  const float* b1 = (const float*)d_in[4];
    const float* W2 = (const float*)d_in[5];  const float* b2 = (const float*)d_in[6];
    const float* W3 = (const float*)d_in[7];  const float* b3 = (const float*)d_in[8];
    const float* Wlin = (const float*)d_in[9]; const float* blin = (const float*)d_in[10];
    float* out = (float*)d_out;

    char* w = (char*)d_ws;
    size_t off = 0;
    auto alloc = [&](size_t bytes) { void* p = w + off; off += (bytes + 255) & ~(size_t)255; return p; };
    float* dinv    = (float*)alloc(N_NODES * 4);
    int*   counts  = (int*)alloc(N_NODES * 4);
    int*   row_ptr = (int*)alloc((N_NODES + 1) * 4);
    int*   offs    = (int*)alloc(N_NODES * 4);
    int*   partials= (int*)alloc(256 * 4);
    int2*  e2      = (int2*)alloc((size_t)N_EDGES * 8);
    float* bufA    = (float*)alloc((size_t)N_NODES * D * 4);
    float* bufB    = (float*)alloc((size_t)N_NODES * D * 4);
    float* psum    = (float*)alloc(N_GRAPHS * D * 4);
    float* pcnt    = (float*)alloc(N_GRAPHS * 4);

    hipMemsetAsync(counts, 0, N_NODES * 4, stream);
    hipMemsetAsync(psum, 0, N_GRAPHS * D * 4, stream);
    hipMemsetAsync(pcnt, 0, N_GRAPHS * 4, stream);

    const int EB = (N_EDGES + 255) / 256;   // 3125
    k_count<<<EB, 256, 0, stream>>>(col, counts);
    k_dinv<<<NCHUNK, 256, 0, stream>>>(counts, dinv);
    k_chunksum<<<NCHUNK, 256, 0, stream>>>(counts, partials);
    k_scanpart<<<1, 256, 0, stream>>>(partials, NCHUNK);
    k_scanchunk<<<NCHUNK, 256, 0, stream>>>(counts, partials, row_ptr, offs);
    k_fill<<<EB, 256, 0, stream>>>(row, col, dinv, offs, e2);

    const int GB = (N_NODES + 31) / 32;        // 1563 gemm blocks
    const int AB = (N_NODES * 64 + 255) / 256; // 12500 agg blocks (1 wave/node)
    const int PB = (N_NODES + 31) / 32;        // 1563 pool blocks

    k_gemm<<<GB, 256, 0, stream>>>(x, W1, bufA, N_NODES);
    k_agg<1><<<AB, 256, 0, stream>>>(bufA, row_ptr, e2, dinv, b1, bufB);
    k_gemm<<<GB, 256, 0, stream>>>(bufB, W2, bufA, N_NODES);
    k_agg<1><<<AB, 256, 0, stream>>>(bufA, row_ptr, e2, dinv, b2, bufB);
    k_gemm<<<GB, 256, 0, stream>>>(bufB, W3, bufA, N_NODES);
    k_agg<0><<<AB, 256, 0, stream>>>(bufA, row_ptr, e2, dinv, b3, bufB);

    k_pool<<<PB, 64, 0, stream>>>(bufB, batch, psum, pcnt);
    k_final<<<1, 384, 0, stream>>>(psum, pcnt, Wlin, blin, out);
}

// Round 5
// 479.888 us; speedup vs baseline: 1.1680x; 1.0926x over previous
//
#include <hip/hip_runtime.h>

#define N_NODES 50000
#define N_EDGES 800000
#define N_GRAPHS 128
#define D 128
#define NCHUNK 196           // ceil(50000/256)

__device__ __forceinline__ void fma4(float4& a, float w, const float4& h) {
    a.x += w * h.x; a.y += w * h.y; a.z += w * h.z; a.w += w * h.w;
}
__device__ __forceinline__ void add4(float4& a, const float4& h) {
    a.x += h.x; a.y += h.y; a.z += h.z; a.w += h.w;
}

// ---------------------------------------------------------------- CSR build
__global__ __launch_bounds__(256) void k_count(const int* __restrict__ col,
                                               int* __restrict__ counts) {
    int e = blockIdx.x * 256 + threadIdx.x;
    if (e < N_EDGES) atomicAdd(&counts[col[e]], 1);
}

__global__ __launch_bounds__(256) void k_dinv(const int* __restrict__ counts,
                                              float* __restrict__ dinv) {
    int i = blockIdx.x * 256 + threadIdx.x;
    if (i < N_NODES) dinv[i] = rsqrtf((float)(counts[i] + 1)); // +1 self loop
}

__global__ __launch_bounds__(256) void k_chunksum(const int* __restrict__ counts,
                                                  int* __restrict__ partials) {
    __shared__ int s[256];
    int i = blockIdx.x * 256 + threadIdx.x;
    s[threadIdx.x] = (i < N_NODES) ? counts[i] : 0;
    __syncthreads();
    for (int off = 128; off > 0; off >>= 1) {
        if (threadIdx.x < off) s[threadIdx.x] += s[threadIdx.x + off];
        __syncthreads();
    }
    if (threadIdx.x == 0) partials[blockIdx.x] = s[0];
}

__global__ __launch_bounds__(256) void k_scanpart(int* __restrict__ partials, int m) {
    __shared__ int s[256];
    int t = threadIdx.x;
    int orig = (t < m) ? partials[t] : 0;
    s[t] = orig;
    __syncthreads();
    for (int off = 1; off < 256; off <<= 1) {
        int v = (t >= off) ? s[t - off] : 0;
        __syncthreads();
        s[t] += v;
        __syncthreads();
    }
    if (t < m) partials[t] = s[t] - orig;   // exclusive
}

__global__ __launch_bounds__(256) void k_scanchunk(const int* __restrict__ counts,
                                                   const int* __restrict__ partials,
                                                   int* __restrict__ row_ptr,
                                                   int* __restrict__ offs) {
    __shared__ int s[256];
    int i = blockIdx.x * 256 + threadIdx.x;
    int t = threadIdx.x;
    int orig = (i < N_NODES) ? counts[i] : 0;
    s[t] = orig;
    __syncthreads();
    for (int off = 1; off < 256; off <<= 1) {
        int v = (t >= off) ? s[t - off] : 0;
        __syncthreads();
        s[t] += v;
        __syncthreads();
    }
    int ex = s[t] - orig + partials[blockIdx.x];
    if (i < N_NODES) { row_ptr[i] = ex; offs[i] = ex; }
    if (i == N_NODES - 1) row_ptr[N_NODES] = ex + orig;
}

__global__ __launch_bounds__(256) void k_fill(const int* __restrict__ row,
                                              const int* __restrict__ col,
                                              int* __restrict__ offs,
                                              int* __restrict__ esrc) {
    int e = blockIdx.x * 256 + threadIdx.x;
    if (e < N_EDGES) {
        int c = col[e];
        int pos = atomicAdd(&offs[c], 1);
        esrc[pos] = row[e];
    }
}

// ---------------------------------------------------------------- GEMM  y = dinv ⊙ (H @ W)
// Block: 256 threads, 64 rows x 64 cols tile. W half (128x64 = 32 KB) staged once in LDS.
// H read directly from global (addresses uniform across the 16 col-lanes -> HW broadcast, L1).
// 5 blocks/CU (32 KB LDS, VGPR capped by launch_bounds) -> 20 waves/CU, no inner barriers.
__global__ __launch_bounds__(256, 5) void k_gemm(const float* __restrict__ H,
                                                 const float* __restrict__ W,
                                                 const float* __restrict__ dinv,
                                                 float* __restrict__ out, int n) {
    __shared__ float Ws[128 * 64];    // 32 KB, k-major within the column half
    const int tid = threadIdx.x;
    const int half = blockIdx.x & 1;           // which 64-column half
    const int row0 = (blockIdx.x >> 1) * 64;   // 64-row tile
    {
        const float4* W4 = (const float4*)W;   // W row stride = 32 float4
        float4* Ws4 = (float4*)Ws;
#pragma unroll
        for (int i = 0; i < 8; ++i) {
            int idx = i * 256 + tid;           // 0..2047
            int k = idx >> 4, c4 = idx & 15;
            Ws4[idx] = W4[k * 32 + half * 16 + c4];
        }
    }
    __syncthreads();
    const int tx = tid & 15;                   // col group: 4 cols
    const int ty = tid >> 4;                   // row group: 4 rows (16 groups = 64 rows)
    const float4* H4 = (const float4*)H;
    const float4* Ws4 = (const float4*)Ws;
    const int r0 = row0 + ty * 4;
    const size_t ra = (size_t)min(r0 + 0, n - 1) * 32;
    const size_t rb = (size_t)min(r0 + 1, n - 1) * 32;
    const size_t rc = (size_t)min(r0 + 2, n - 1) * 32;
    const size_t rd = (size_t)min(r0 + 3, n - 1) * 32;
    float4 acc0 = {0,0,0,0}, acc1 = {0,0,0,0}, acc2 = {0,0,0,0}, acc3 = {0,0,0,0};
#pragma unroll 2
    for (int k4 = 0; k4 < 32; ++k4) {
        float4 a0 = H4[ra + k4];
        float4 a1 = H4[rb + k4];
        float4 a2 = H4[rc + k4];
        float4 a3 = H4[rd + k4];
        float4 b0 = Ws4[(k4 * 4 + 0) * 16 + tx];
        float4 b1 = Ws4[(k4 * 4 + 1) * 16 + tx];
        float4 b2 = Ws4[(k4 * 4 + 2) * 16 + tx];
        float4 b3 = Ws4[(k4 * 4 + 3) * 16 + tx];
        fma4(acc0, a0.x, b0); fma4(acc0, a0.y, b1); fma4(acc0, a0.z, b2); fma4(acc0, a0.w, b3);
        fma4(acc1, a1.x, b0); fma4(acc1, a1.y, b1); fma4(acc1, a1.z, b2); fma4(acc1, a1.w, b3);
        fma4(acc2, a2.x, b0); fma4(acc2, a2.y, b1); fma4(acc2, a2.z, b2); fma4(acc2, a2.w, b3);
        fma4(acc3, a3.x, b0); fma4(acc3, a3.y, b1); fma4(acc3, a3.z, b2); fma4(acc3, a3.w, b3);
    }
    float4* o4 = (float4*)out;
    const int co = half * 16 + tx;
    if (r0 + 0 < n) { float d = dinv[r0 + 0]; acc0.x *= d; acc0.y *= d; acc0.z *= d; acc0.w *= d; o4[(size_t)(r0 + 0) * 32 + co] = acc0; }
    if (r0 + 1 < n) { float d = dinv[r0 + 1]; acc1.x *= d; acc1.y *= d; acc1.z *= d; acc1.w *= d; o4[(size_t)(r0 + 1) * 32 + co] = acc1; }
    if (r0 + 2 < n) { float d = dinv[r0 + 2]; acc2.x *= d; acc2.y *= d; acc2.z *= d; acc2.w *= d; o4[(size_t)(r0 + 2) * 32 + co] = acc2; }
    if (r0 + 3 < n) { float d = dinv[r0 + 3]; acc3.x *= d; acc3.y *= d; acc3.z *= d; acc3.w *= d; o4[(size_t)(r0 + 3) * 32 + co] = acc3; }
}

// ---------------------------------------------------------------- aggregation
// y = dinv ⊙ HW already; out[c] = dinv[c] * (Σ_{r∈N(c)} y[r] + y[c]) + b
// one wave per node; half-wave per edge-row (float4 per lane = 512 B row); no weights.
template <int RELU>
__global__ __launch_bounds__(256) void k_agg(const float* __restrict__ Y,
                                             const int* __restrict__ rp,
                                             const int* __restrict__ esrc,
                                             const float* __restrict__ dinv,
                                             const float* __restrict__ bias,
                                             float* __restrict__ out) {
    int wid = (blockIdx.x * 256 + threadIdx.x) >> 6;
    int c = __builtin_amdgcn_readfirstlane(wid);
    if (c >= N_NODES) return;
    const int lane = threadIdx.x & 63;
    const int half = lane >> 5;
    const int l = lane & 31;
    const float4* __restrict__ Y4 = (const float4*)Y;
    const int beg = rp[c], end = rp[c + 1];
    float4 acc0 = {0,0,0,0}, acc1 = {0,0,0,0};
    int jj = beg + half;                     // half 0: even slots, half 1: odd slots
    for (; jj + 2 < end; jj += 4) {
        int s0 = esrc[jj];
        int s1 = esrc[jj + 2];
        float4 h0 = Y4[(size_t)s0 * 32 + l];
        float4 h1 = Y4[(size_t)s1 * 32 + l];
        add4(acc0, h0);
        add4(acc1, h1);
    }
    for (; jj < end; jj += 2) add4(acc0, Y4[(size_t)esrc[jj] * 32 + l]);
    if (half == 0) add4(acc0, Y4[(size_t)c * 32 + l]);   // self loop: + y[c]
    add4(acc0, acc1);
    acc0.x += __shfl_xor(acc0.x, 32);
    acc0.y += __shfl_xor(acc0.y, 32);
    acc0.z += __shfl_xor(acc0.z, 32);
    acc0.w += __shfl_xor(acc0.w, 32);
    if (half == 0) {
        const float dv = dinv[c];
        float4 bb = ((const float4*)bias)[l];
        float4 r;
        r.x = dv * acc0.x + bb.x;
        r.y = dv * acc0.y + bb.y;
        r.z = dv * acc0.z + bb.z;
        r.w = dv * acc0.w + bb.w;
        if (RELU) {
            r.x = fmaxf(r.x, 0.f); r.y = fmaxf(r.y, 0.f);
            r.z = fmaxf(r.z, 0.f); r.w = fmaxf(r.w, 0.f);
        }
        ((float4*)out)[(size_t)c * 32 + l] = r;
    }
}

// ---------------------------------------------------------------- mean pool (sorted batch)
__global__ __launch_bounds__(64) void k_pool(const float* __restrict__ h,
                                             const int* __restrict__ batch,
                                             float* __restrict__ psum,
                                             float* __restrict__ pcnt) {
    const int l = threadIdx.x;                 // 64 lanes, float2 each = 128 dims
    const int start = blockIdx.x * 32;
    if (start >= N_NODES) return;
    const int end = min(start + 32, N_NODES);
    const float2* __restrict__ h2 = (const float2*)h;
    float2 acc = {0.f, 0.f};
    float cnt = 0.f;
    int g = batch[start];
    for (int i = start; i < end; ++i) {
        int gi = batch[i];
        if (gi != g) {
            atomicAdd(&psum[g * D + 2 * l], acc.x);
            atomicAdd(&psum[g * D + 2 * l + 1], acc.y);
            if (l == 0) atomicAdd(&pcnt[g], cnt);
            acc.x = 0.f; acc.y = 0.f; cnt = 0.f; g = gi;
        }
        float2 v = h2[(size_t)i * 64 + l];
        acc.x += v.x; acc.y += v.y; cnt += 1.f;
    }
    atomicAdd(&psum[g * D + 2 * l], acc.x);
    atomicAdd(&psum[g * D + 2 * l + 1], acc.y);
    if (l == 0) atomicAdd(&pcnt[g], cnt);
}

__global__ __launch_bounds__(384) void k_final(const float* __restrict__ psum,
                                               const float* __restrict__ pcnt,
                                               const float* __restrict__ Wlin,
                                               const float* __restrict__ blin,
                                               float* __restrict__ out) {
    int t = threadIdx.x;
    if (t >= N_GRAPHS * 3) return;
    int g = t / 3, o = t % 3;
    float c = fmaxf(pcnt[g], 1.f);
    float acc = 0.f;
#pragma unroll 8
    for (int d = 0; d < D; ++d) acc += psum[g * D + d] * Wlin[d * 3 + o];
    out[t] = acc / c + blin[o];
}

// ---------------------------------------------------------------- launch
extern "C" void kernel_launch(void* const* d_in, const int* in_sizes, int n_in,
                              void* d_out, int out_size, void* d_ws, size_t ws_size,
                              hipStream_t stream) {
    const float* x    = (const float*)d_in[0];
    const int*   row  = (const int*)d_in[1];             // edge_index[0]
    const int*   col  = ((const int*)d_in[1]) + N_EDGES; // edge_index[1]
    const int*   batch = (const int*)d_in[2];
    const float* W1 = (const float*)d_in[3];  const float* b1 = (const float*)d_in[4];
    const float* W2 = (const float*)d_in[5];  const float* b2 = (const float*)d_in[6];
    const float* W3 = (const float*)d_in[7];  const float* b3 = (const float*)d_in[8];
    const float* Wlin = (const float*)d_in[9]; const float* blin = (const float*)d_in[10];
    float* out = (float*)d_out;

    char* w = (char*)d_ws;
    size_t off = 0;
    auto alloc = [&](size_t bytes) { void* p = w + off; off += (bytes + 255) & ~(size_t)255; return p; };
    float* dinv    = (float*)alloc(N_NODES * 4);
    int*   counts  = (int*)alloc(N_NODES * 4);
    int*   row_ptr = (int*)alloc((N_NODES + 1) * 4);
    int*   offs    = (int*)alloc(N_NODES * 4);
    int*   partials= (int*)alloc(256 * 4);
    int*   esrc    = (int*)alloc((size_t)N_EDGES * 4);
    float* bufA    = (float*)alloc((size_t)N_NODES * D * 4);
    float* bufB    = (float*)alloc((size_t)N_NODES * D * 4);
    float* psum    = (float*)alloc(N_GRAPHS * D * 4);
    float* pcnt    = (float*)alloc(N_GRAPHS * 4);

    hipMemsetAsync(counts, 0, N_NODES * 4, stream);
    hipMemsetAsync(psum, 0, N_GRAPHS * D * 4, stream);
    hipMemsetAsync(pcnt, 0, N_GRAPHS * 4, stream);

    const int EB = (N_EDGES + 255) / 256;   // 3125
    k_count<<<EB, 256, 0, stream>>>(col, counts);
    k_dinv<<<NCHUNK, 256, 0, stream>>>(counts, dinv);
    k_chunksum<<<NCHUNK, 256, 0, stream>>>(counts, partials);
    k_scanpart<<<1, 256, 0, stream>>>(partials, NCHUNK);
    k_scanchunk<<<NCHUNK, 256, 0, stream>>>(counts, partials, row_ptr, offs);
    k_fill<<<EB, 256, 0, stream>>>(row, col, offs, esrc);

    const int GB = ((N_NODES + 63) / 64) * 2;  // 782 row-tiles x 2 col-halves = 1564
    const int AB = (N_NODES * 64 + 255) / 256; // 12500 agg blocks (1 wave/node)
    const int PB = (N_NODES + 31) / 32;        // 1563 pool blocks

    k_gemm<<<GB, 256, 0, stream>>>(x, W1, dinv, bufA, N_NODES);
    k_agg<1><<<AB, 256, 0, stream>>>(bufA, row_ptr, esrc, dinv, b1, bufB);
    k_gemm<<<GB, 256, 0, stream>>>(bufB, W2, dinv, bufA, N_NODES);
    k_agg<1><<<AB, 256, 0, stream>>>(bufA, row_ptr, esrc, dinv, b2, bufB);
    k_gemm<<<GB, 256, 0, stream>>>(bufB, W3, dinv, bufA, N_NODES);
    k_agg<0><<<AB, 256, 0, stream>>>(bufA, row_ptr, esrc, dinv, b3, bufB);

    k_pool<<<PB, 64, 0, stream>>>(bufB, batch, psum, pcnt);
    k_final<<<1, 384, 0, stream>>>(psum, pcnt, Wlin, blin, out);
}

// Round 7
// 477.620 us; speedup vs baseline: 1.1736x; 1.0047x over previous
//
#include <hip/hip_runtime.h>

#define N_NODES 50000
#define N_EDGES 800000
#define N_GRAPHS 128
#define D 128
#define NCHUNK 196           // ceil(50000/256)

__device__ __forceinline__ void fma4(float4& a, float w, const float4& h) {
    a.x += w * h.x; a.y += w * h.y; a.z += w * h.z; a.w += w * h.w;
}
__device__ __forceinline__ void add4(float4& a, const float4& h) {
    a.x += h.x; a.y += h.y; a.z += h.z; a.w += h.w;
}

// ---------------------------------------------------------------- CSR build
__global__ __launch_bounds__(256) void k_count(const int* __restrict__ col,
                                               int* __restrict__ counts) {
    int e = blockIdx.x * 256 + threadIdx.x;
    if (e < N_EDGES) atomicAdd(&counts[col[e]], 1);
}

__global__ __launch_bounds__(256) void k_dinv(const int* __restrict__ counts,
                                              float* __restrict__ dinv) {
    int i = blockIdx.x * 256 + threadIdx.x;
    if (i < N_NODES) dinv[i] = rsqrtf((float)(counts[i] + 1)); // +1 self loop
}

__global__ __launch_bounds__(256) void k_chunksum(const int* __restrict__ counts,
                                                  int* __restrict__ partials) {
    __shared__ int s[256];
    int i = blockIdx.x * 256 + threadIdx.x;
    s[threadIdx.x] = (i < N_NODES) ? counts[i] : 0;
    __syncthreads();
    for (int off = 128; off > 0; off >>= 1) {
        if (threadIdx.x < off) s[threadIdx.x] += s[threadIdx.x + off];
        __syncthreads();
    }
    if (threadIdx.x == 0) partials[blockIdx.x] = s[0];
}

__global__ __launch_bounds__(256) void k_scanpart(int* __restrict__ partials, int m) {
    __shared__ int s[256];
    int t = threadIdx.x;
    int orig = (t < m) ? partials[t] : 0;
    s[t] = orig;
    __syncthreads();
    for (int off = 1; off < 256; off <<= 1) {
        int v = (t >= off) ? s[t - off] : 0;
        __syncthreads();
        s[t] += v;
        __syncthreads();
    }
    if (t < m) partials[t] = s[t] - orig;   // exclusive
}

__global__ __launch_bounds__(256) void k_scanchunk(const int* __restrict__ counts,
                                                   const int* __restrict__ partials,
                                                   int* __restrict__ row_ptr,
                                                   int* __restrict__ offs) {
    __shared__ int s[256];
    int i = blockIdx.x * 256 + threadIdx.x;
    int t = threadIdx.x;
    int orig = (i < N_NODES) ? counts[i] : 0;
    s[t] = orig;
    __syncthreads();
    for (int off = 1; off < 256; off <<= 1) {
        int v = (t >= off) ? s[t - off] : 0;
        __syncthreads();
        s[t] += v;
        __syncthreads();
    }
    int ex = s[t] - orig + partials[blockIdx.x];
    if (i < N_NODES) { row_ptr[i] = ex; offs[i] = ex; }
    if (i == N_NODES - 1) row_ptr[N_NODES] = ex + orig;
}

__global__ __launch_bounds__(256) void k_fill(const int* __restrict__ row,
                                              const int* __restrict__ col,
                                              int* __restrict__ offs,
                                              int* __restrict__ esrc) {
    int e = blockIdx.x * 256 + threadIdx.x;
    if (e < N_EDGES) {
        int c = col[e];
        int pos = atomicAdd(&offs[c], 1);
        esrc[pos] = row[e];
    }
}

// ---------------------------------------------------------------- GEMM  y = dinv ⊙ (H @ W)
// Block: 256 threads, 64 rows x 64 cols tile. W half (128x64 = 32 KB) staged once in LDS.
// H read directly from global (addresses uniform across the 16 col-lanes -> coalesced/broadcast).
__global__ __launch_bounds__(256, 5) void k_gemm(const float* __restrict__ H,
                                                 const float* __restrict__ W,
                                                 const float* __restrict__ dinv,
                                                 float* __restrict__ out, int n) {
    __shared__ float Ws[128 * 64];    // 32 KB, k-major within the column half
    const int tid = threadIdx.x;
    const int half = blockIdx.x & 1;           // which 64-column half
    const int row0 = (blockIdx.x >> 1) * 64;   // 64-row tile
    {
        const float4* W4 = (const float4*)W;   // W row stride = 32 float4
        float4* Ws4 = (float4*)Ws;
#pragma unroll
        for (int i = 0; i < 8; ++i) {
            int idx = i * 256 + tid;           // 0..2047
            int k = idx >> 4, c4 = idx & 15;
            Ws4[idx] = W4[k * 32 + half * 16 + c4];
        }
    }
    __syncthreads();
    const int tx = tid & 15;                   // col group: 4 cols
    const int ty = tid >> 4;                   // row group: 4 rows (16 groups = 64 rows)
    const float4* H4 = (const float4*)H;
    const float4* Ws4 = (const float4*)Ws;
    const int r0 = row0 + ty * 4;
    const size_t ra = (size_t)min(r0 + 0, n - 1) * 32;
    const size_t rb = (size_t)min(r0 + 1, n - 1) * 32;
    const size_t rc = (size_t)min(r0 + 2, n - 1) * 32;
    const size_t rd = (size_t)min(r0 + 3, n - 1) * 32;
    float4 acc0 = {0,0,0,0}, acc1 = {0,0,0,0}, acc2 = {0,0,0,0}, acc3 = {0,0,0,0};
#pragma unroll 2
    for (int k4 = 0; k4 < 32; ++k4) {
        float4 a0 = H4[ra + k4];
        float4 a1 = H4[rb + k4];
        float4 a2 = H4[rc + k4];
        float4 a3 = H4[rd + k4];
        float4 b0 = Ws4[(k4 * 4 + 0) * 16 + tx];
        float4 b1 = Ws4[(k4 * 4 + 1) * 16 + tx];
        float4 b2 = Ws4[(k4 * 4 + 2) * 16 + tx];
        float4 b3 = Ws4[(k4 * 4 + 3) * 16 + tx];
        fma4(acc0, a0.x, b0); fma4(acc0, a0.y, b1); fma4(acc0, a0.z, b2); fma4(acc0, a0.w, b3);
        fma4(acc1, a1.x, b0); fma4(acc1, a1.y, b1); fma4(acc1, a1.z, b2); fma4(acc1, a1.w, b3);
        fma4(acc2, a2.x, b0); fma4(acc2, a2.y, b1); fma4(acc2, a2.z, b2); fma4(acc2, a2.w, b3);
        fma4(acc3, a3.x, b0); fma4(acc3, a3.y, b1); fma4(acc3, a3.z, b2); fma4(acc3, a3.w, b3);
    }
    float4* o4 = (float4*)out;
    const int co = half * 16 + tx;
    if (r0 + 0 < n) { float d = dinv[r0 + 0]; acc0.x *= d; acc0.y *= d; acc0.z *= d; acc0.w *= d; o4[(size_t)(r0 + 0) * 32 + co] = acc0; }
    if (r0 + 1 < n) { float d = dinv[r0 + 1]; acc1.x *= d; acc1.y *= d; acc1.z *= d; acc1.w *= d; o4[(size_t)(r0 + 1) * 32 + co] = acc1; }
    if (r0 + 2 < n) { float d = dinv[r0 + 2]; acc2.x *= d; acc2.y *= d; acc2.z *= d; acc2.w *= d; o4[(size_t)(r0 + 2) * 32 + co] = acc2; }
    if (r0 + 3 < n) { float d = dinv[r0 + 3]; acc3.x *= d; acc3.y *= d; acc3.z *= d; acc3.w *= d; o4[(size_t)(r0 + 3) * 32 + co] = acc3; }
}

// ---------------------------------------------------------------- aggregation
// out[c] = dinv[c] * (Σ_{r∈N(c)} y[r] + y[c]) + b,  y = dinv ⊙ HW (from gemm epilogue)
// one wave per node; half-wave per edge-row (float4/lane = 512 B row);
// 4 row-gathers in flight per half (MLP=4) with independent accumulator chains.
template <int RELU>
__global__ __launch_bounds__(256) void k_agg(const float* __restrict__ Y,
                                             const int* __restrict__ rp,
                                             const int* __restrict__ esrc,
                                             const float* __restrict__ dinv,
                                             const float* __restrict__ bias,
                                             float* __restrict__ out) {
    int wid = (blockIdx.x * 256 + threadIdx.x) >> 6;
    int c = __builtin_amdgcn_readfirstlane(wid);
    if (c >= N_NODES) return;
    const int lane = threadIdx.x & 63;
    const int half = lane >> 5;
    const int l = lane & 31;
    const float4* __restrict__ Y4 = (const float4*)Y;
    const int beg = rp[c], end = rp[c + 1];
    float4 A0 = {0,0,0,0}, A1 = {0,0,0,0}, A2 = {0,0,0,0}, A3 = {0,0,0,0};
    int jj = beg + half;                     // half 0: even slots, half 1: odd slots
    for (; jj + 6 < end; jj += 8) {          // 4 slots per half per iteration
        int s0 = esrc[jj];
        int s1 = esrc[jj + 2];
        int s2 = esrc[jj + 4];
        int s3 = esrc[jj + 6];
        float4 h0 = Y4[(size_t)s0 * 32 + l];
        float4 h1 = Y4[(size_t)s1 * 32 + l];
        float4 h2 = Y4[(size_t)s2 * 32 + l];
        float4 h3 = Y4[(size_t)s3 * 32 + l];
        add4(A0, h0);
        add4(A1, h1);
        add4(A2, h2);
        add4(A3, h3);
    }
    if (jj + 2 < end) {                      // 2 remaining slots for this half
        int s0 = esrc[jj];
        int s1 = esrc[jj + 2];
        float4 h0 = Y4[(size_t)s0 * 32 + l];
        float4 h1 = Y4[(size_t)s1 * 32 + l];
        add4(A0, h0);
        add4(A1, h1);
        jj += 4;
    }
    if (jj < end) add4(A2, Y4[(size_t)esrc[jj] * 32 + l]);
    if (half == 0) add4(A3, Y4[(size_t)c * 32 + l]);   // self loop: + y[c]
    add4(A0, A1);
    add4(A2, A3);
    add4(A0, A2);
    A0.x += __shfl_xor(A0.x, 32);
    A0.y += __shfl_xor(A0.y, 32);
    A0.z += __shfl_xor(A0.z, 32);
    A0.w += __shfl_xor(A0.w, 32);
    if (half == 0) {
        const float dv = dinv[c];
        float4 bb = ((const float4*)bias)[l];
        float4 r;
        r.x = dv * A0.x + bb.x;
        r.y = dv * A0.y + bb.y;
        r.z = dv * A0.z + bb.z;
        r.w = dv * A0.w + bb.w;
        if (RELU) {
            r.x = fmaxf(r.x, 0.f); r.y = fmaxf(r.y, 0.f);
            r.z = fmaxf(r.z, 0.f); r.w = fmaxf(r.w, 0.f);
        }
        ((float4*)out)[(size_t)c * 32 + l] = r;
    }
}

// ---------------------------------------------------------------- mean pool (sorted batch)
__global__ __launch_bounds__(64) void k_pool(const float* __restrict__ h,
                                             const int* __restrict__ batch,
                                             float* __restrict__ psum,
                                             float* __restrict__ pcnt) {
    const int l = threadIdx.x;                 // 64 lanes, float2 each = 128 dims
    const int start = blockIdx.x * 32;
    if (start >= N_NODES) return;
    const int end = min(start + 32, N_NODES);
    const float2* __restrict__ h2 = (const float2*)h;
    float2 acc = {0.f, 0.f};
    float cnt = 0.f;
    int g = batch[start];
    for (int i = start; i < end; ++i) {
        int gi = batch[i];
        if (gi != g) {
            atomicAdd(&psum[g * D + 2 * l], acc.x);
            atomicAdd(&psum[g * D + 2 * l + 1], acc.y);
            if (l == 0) atomicAdd(&pcnt[g], cnt);
            acc.x = 0.f; acc.y = 0.f; cnt = 0.f; g = gi;
        }
        float2 v = h2[(size_t)i * 64 + l];
        acc.x += v.x; acc.y += v.y; cnt += 1.f;
    }
    atomicAdd(&psum[g * D + 2 * l], acc.x);
    atomicAdd(&psum[g * D + 2 * l + 1], acc.y);
    if (l == 0) atomicAdd(&pcnt[g], cnt);
}

__global__ __launch_bounds__(384) void k_final(const float* __restrict__ psum,
                                               const float* __restrict__ pcnt,
                                               const float* __restrict__ Wlin,
                                               const float* __restrict__ blin,
                                               float* __restrict__ out) {
    int t = threadIdx.x;
    if (t >= N_GRAPHS * 3) return;
    int g = t / 3, o = t % 3;
    float c = fmaxf(pcnt[g], 1.f);
    float acc = 0.f;
#pragma unroll 8
    for (int d = 0; d < D; ++d) acc += psum[g * D + d] * Wlin[d * 3 + o];
    out[t] = acc / c + blin[o];
}

// ---------------------------------------------------------------- launch
extern "C" void kernel_launch(void* const* d_in, const int* in_sizes, int n_in,
                              void* d_out, int out_size, void* d_ws, size_t ws_size,
                              hipStream_t stream) {
    const float* x    = (const float*)d_in[0];
    const int*   row  = (const int*)d_in[1];             // edge_index[0]
    const int*   col  = ((const int*)d_in[1]) + N_EDGES; // edge_index[1]
    const int*   batch = (const int*)d_in[2];
    const float* W1 = (const float*)d_in[3];  const float* b1 = (const float*)d_in[4];
    const float* W2 = (const float*)d_in[5];  const float* b2 = (const float*)d_in[6];
    const float* W3 = (const float*)d_in[7];  const float* b3 = (const float*)d_in[8];
    const float* Wlin = (const float*)d_in[9]; const float* blin = (const float*)d_in[10];
    float* out = (float*)d_out;

    char* w = (char*)d_ws;
    size_t off = 0;
    auto alloc = [&](size_t bytes) { void* p = w + off; off += (bytes + 255) & ~(size_t)255; return p; };
    float* dinv    = (float*)alloc(N_NODES * 4);
    int*   counts  = (int*)alloc(N_NODES * 4);
    int*   row_ptr = (int*)alloc((N_NODES + 1) * 4);
    int*   offs    = (int*)alloc(N_NODES * 4);
    int*   partials= (int*)alloc(256 * 4);
    int*   esrc    = (int*)alloc((size_t)N_EDGES * 4);
    float* bufA    = (float*)alloc((size_t)N_NODES * D * 4);
    float* bufB    = (float*)alloc((size_t)N_NODES * D * 4);
    float* psum    = (float*)alloc(N_GRAPHS * D * 4);
    float* pcnt    = (float*)alloc(N_GRAPHS * 4);

    hipMemsetAsync(counts, 0, N_NODES * 4, stream);
    hipMemsetAsync(psum, 0, N_GRAPHS * D * 4, stream);
    hipMemsetAsync(pcnt, 0, N_GRAPHS * 4, stream);

    const int EB = (N_EDGES + 255) / 256;   // 3125
    k_count<<<EB, 256, 0, stream>>>(col, counts);
    k_dinv<<<NCHUNK, 256, 0, stream>>>(counts, dinv);
    k_chunksum<<<NCHUNK, 256, 0, stream>>>(counts, partials);
    k_scanpart<<<1, 256, 0, stream>>>(partials, NCHUNK);
    k_scanchunk<<<NCHUNK, 256, 0, stream>>>(counts, partials, row_ptr, offs);
    k_fill<<<EB, 256, 0, stream>>>(row, col, offs, esrc);

    const int GB = ((N_NODES + 63) / 64) * 2;  // 782 row-tiles x 2 col-halves = 1564
    const int AB = (N_NODES * 64 + 255) / 256; // 12500 agg blocks (1 wave/node)
    const int PB = (N_NODES + 31) / 32;        // 1563 pool blocks

    k_gemm<<<GB, 256, 0, stream>>>(x, W1, dinv, bufA, N_NODES);
    k_agg<1><<<AB, 256, 0, stream>>>(bufA, row_ptr, esrc, dinv, b1, bufB);
    k_gemm<<<GB, 256, 0, stream>>>(bufB, W2, dinv, bufA, N_NODES);
    k_agg<1><<<AB, 256, 0, stream>>>(bufA, row_ptr, esrc, dinv, b2, bufB);
    k_gemm<<<GB, 256, 0, stream>>>(bufB, W3, dinv, bufA, N_NODES);
    k_agg<0><<<AB, 256, 0, stream>>>(bufA, row_ptr, esrc, dinv, b3, bufB);

    k_pool<<<PB, 64, 0, stream>>>(bufB, batch, psum, pcnt);
    k_final<<<1, 384, 0, stream>>>(psum, pcnt, Wlin, blin, out);
}